// Round 2
// baseline (189.541 us; speedup 1.0000x reference)
//
#include <hip/hip_runtime.h>
#include <stdint.h>

// ---------------------------------------------------------------------------
// Threefry-2x32 (20 rounds), bit-exact match of JAX's implementation.
// ---------------------------------------------------------------------------
__device__ __forceinline__ void threefry2x32(uint32_t k0, uint32_t k1,
                                             uint32_t& x0, uint32_t& x1) {
  const uint32_t ks2 = k0 ^ k1 ^ 0x1BD11BDAu;
  uint32_t ks[3] = {k0, k1, ks2};
  const int rot[8] = {13, 15, 26, 6, 17, 29, 16, 24};
  x0 += ks[0];
  x1 += ks[1];
#pragma unroll
  for (int i = 0; i < 5; ++i) {
#pragma unroll
    for (int j = 0; j < 4; ++j) {
      const int r = rot[(i & 1) * 4 + j];
      x0 += x1;
      x1 = (x1 << r) | (x1 >> (32 - r));
      x1 ^= x0;
    }
    x0 += ks[(i + 1) % 3];
    x1 += ks[(i + 2) % 3] + (uint32_t)(i + 1);
  }
}

// masked = (uniform(fold_in(key42,i), shape) < 0.8) * eps / 0.8
// JAX >= 0.4.30 defaults jax_threefry_partitionable=True: random_bits is a
// per-element PRF. Element e uses 64-bit counter e -> threefry input
// (hi32(e), lo32(e)) = (0, e) here; the two 32-bit outputs are XOR-folded.
// fold_in is unchanged by the flag: new_key = threefry(key, [0, i]).
__global__ void mask_kernel(const float* __restrict__ eps0,
                            const float* __restrict__ eps1,
                            float* __restrict__ e0m, float* __restrict__ e1m) {
  int idx = blockIdx.x * blockDim.x + threadIdx.x;
  int core, e;
  const float* src;
  float* dst;
  if (idx < 3072) {
    core = 0; e = idx; src = eps0; dst = e0m;
  } else if (idx < 16032) {
    core = 1; e = idx - 3072; src = eps1; dst = e1m;
  } else {
    return;
  }
  // fold_in: key(42) = [0,42]; plaintext = threefry_seed(core) = [0, core]
  uint32_t f0 = 0u, f1 = (uint32_t)core;
  threefry2x32(0u, 42u, f0, f1);
  // partitionable random_bits: counter = e (uint64) -> (x0,x1) = (0, e)
  uint32_t a = 0u, b = (uint32_t)e;
  threefry2x32(f0, f1, a, b);
  uint32_t bits = a ^ b;
  float u = __uint_as_float((bits >> 9) | 0x3F800000u) - 1.0f;
  float m = (u < 0.8f) ? 1.0f : 0.0f;
  dst[e] = src[e] * m / 0.8f;
}

// ---------------------------------------------------------------------------
// Stage 1: h[b,i,j,o] = sum_k e0[o,k] * prod_{p} x[b,i+p/3,j+p%3, bit_p(k)]
// k: 9 binary digits, pixel (0,0) most significant. One thread per window.
// e0 in LDS transposed [k][o] padded to 8 floats -> float4+float2 broadcast.
// ---------------------------------------------------------------------------
__global__ __launch_bounds__(256) void stage1_kernel(
    const float* __restrict__ x, const float* __restrict__ e0m,
    float* __restrict__ h) {
  __shared__ float Es[512 * 8];
  for (int t = threadIdx.x; t < 3072; t += 256) {
    int o = t >> 9, k = t & 511;  // e0m layout [o][k]
    Es[k * 8 + o] = e0m[t];
  }
  __syncthreads();

  const int pid = blockIdx.x * 256 + threadIdx.x;  // grid is exactly 86528
  const int b = pid / 676;
  const int rem = pid - b * 676;
  const int i = rem / 26;
  const int j = rem - i * 26;

  float xv[9][2];
  const float2* x2 = (const float2*)x;  // x[...,q]: q-pairs are contiguous
#pragma unroll
  for (int di = 0; di < 3; ++di)
#pragma unroll
    for (int dj = 0; dj < 3; ++dj) {
      float2 v = x2[(b * 28 + i + di) * 28 + (j + dj)];
      xv[di * 3 + dj][0] = v.x;
      xv[di * 3 + dj][1] = v.y;
    }

  // products of the last 3 digits (pixels 6,7,8); t bit2 -> pixel 6
  float w3[8];
#pragma unroll
  for (int t = 0; t < 8; ++t)
    w3[t] = xv[6][(t >> 2) & 1] * xv[7][(t >> 1) & 1] * xv[8][t & 1];

  float acc0 = 0, acc1 = 0, acc2 = 0, acc3 = 0, acc4 = 0, acc5 = 0;
  for (int u = 0; u < 64; ++u) {  // first 6 digits (u bit5 -> pixel 0)
    float p = ((u & 32) ? xv[0][1] : xv[0][0]);
    p *= ((u & 16) ? xv[1][1] : xv[1][0]);
    p *= ((u & 8) ? xv[2][1] : xv[2][0]);
    p *= ((u & 4) ? xv[3][1] : xv[3][0]);
    p *= ((u & 2) ? xv[4][1] : xv[4][0]);
    p *= ((u & 1) ? xv[5][1] : xv[5][0]);
    const float* eb = &Es[u * 64];
#pragma unroll
    for (int t = 0; t < 8; ++t) {
      const float pw = p * w3[t];
      const float4 a = *(const float4*)(eb + t * 8);
      const float2 c = *(const float2*)(eb + t * 8 + 4);
      acc0 += a.x * pw;
      acc1 += a.y * pw;
      acc2 += a.z * pw;
      acc3 += a.w * pw;
      acc4 += c.x * pw;
      acc5 += c.y * pw;
    }
  }
  float* hp = h + pid * 6;
  hp[0] = acc0; hp[1] = acc1; hp[2] = acc2;
  hp[3] = acc3; hp[4] = acc4; hp[5] = acc5;
}

// 6-way select with constant indices only (avoids scratch for dynamic index)
__device__ __forceinline__ float sel6(const float a[6], int k) {
  float r = a[0];
  r = (k == 1) ? a[1] : r;
  r = (k == 2) ? a[2] : r;
  r = (k == 3) ? a[3] : r;
  r = (k == 4) ? a[4] : r;
  r = (k == 5) ? a[5] : r;
  return r;
}

// ---------------------------------------------------------------------------
// Stage 2: out[b,i,j,o] = sum_{m,n} e1[o, m*36+n] * P01[m] * P23[n]
//   P01[m]=h0[m/6]*h1[m%6] (row i pair), P23[n]=h2[n/6]*h3[n%6] (row i+1).
// Loop n dynamic; m statically unrolled so e1 LDS offsets are immediates.
// e1 in LDS transposed [k][o] padded to 12 floats (62208 B).
// ---------------------------------------------------------------------------
__global__ __launch_bounds__(256) void stage2_kernel(
    const float* __restrict__ h, const float* __restrict__ e1m,
    float* __restrict__ flat) {
  __shared__ float Es[1296 * 12];
  for (int t = threadIdx.x; t < 12960; t += 256) {
    int o = t / 1296, k = t - o * 1296;  // e1m layout [o][k]
    Es[k * 12 + o] = e1m[t];
  }
  __syncthreads();

  const int pid = blockIdx.x * 256 + threadIdx.x;
  if (pid >= 80000) return;
  const int b = pid / 625;
  const int rem = pid - b * 625;
  const int i = rem / 25;
  const int j = rem - i * 25;

  const float* hp = h + ((b * 26 + i) * 26 + j) * 6;
  float h0[6], h1[6], h2[6], h3[6];
#pragma unroll
  for (int t = 0; t < 6; ++t) {
    h0[t] = hp[t];
    h1[t] = hp[6 + t];
    h2[t] = hp[156 + t];  // next row: 26*6
    h3[t] = hp[162 + t];
  }
  float P[36];
#pragma unroll
  for (int a = 0; a < 6; ++a)
#pragma unroll
    for (int c = 0; c < 6; ++c) P[a * 6 + c] = h0[a] * h1[c];

  float acc[10];
#pragma unroll
  for (int o = 0; o < 10; ++o) acc[o] = 0.0f;

  int k10 = 0, k11 = 0;
  for (int n = 0; n < 36; ++n) {
    float T[10];
#pragma unroll
    for (int o = 0; o < 10; ++o) T[o] = 0.0f;
#pragma unroll
    for (int m = 0; m < 36; ++m) {
      const float* e = &Es[(m * 36 + n) * 12];
      const float4 a = *(const float4*)e;
      const float4 bq = *(const float4*)(e + 4);
      const float2 c = *(const float2*)(e + 8);
      const float pm = P[m];
      T[0] += a.x * pm;  T[1] += a.y * pm;  T[2] += a.z * pm;  T[3] += a.w * pm;
      T[4] += bq.x * pm; T[5] += bq.y * pm; T[6] += bq.z * pm; T[7] += bq.w * pm;
      T[8] += c.x * pm;  T[9] += c.y * pm;
    }
    const float w = sel6(h2, k10) * sel6(h3, k11);
#pragma unroll
    for (int o = 0; o < 10; ++o) acc[o] += w * T[o];
    if (++k11 == 6) { k11 = 0; ++k10; }
  }

  float* fp = flat + b * 6250 + (i * 25 + j) * 10;
#pragma unroll
  for (int o = 0; o < 10; ++o) fp[o] = acc[o];
}

// ---------------------------------------------------------------------------
// Linear: out[b,o] = bias[o] + sum_f flat[b,f] * W[o,f]
// One block per batch row; coalesced strided loads; wave shuffle reduce.
// ---------------------------------------------------------------------------
__global__ __launch_bounds__(256) void linear_kernel(
    const float* __restrict__ flat, const float* __restrict__ W,
    const float* __restrict__ bias, float* __restrict__ out) {
  const int b = blockIdx.x;
  const float* fb = flat + b * 6250;
  float acc[10];
#pragma unroll
  for (int o = 0; o < 10; ++o) acc[o] = 0.0f;
  for (int f = threadIdx.x; f < 6250; f += 256) {
    const float v = fb[f];
#pragma unroll
    for (int o = 0; o < 10; ++o) acc[o] += v * W[o * 6250 + f];
  }
#pragma unroll
  for (int o = 0; o < 10; ++o) {
#pragma unroll
    for (int s = 32; s > 0; s >>= 1) acc[o] += __shfl_xor(acc[o], s, 64);
  }
  __shared__ float red[4][10];
  const int lane = threadIdx.x & 63, wv = threadIdx.x >> 6;
  if (lane == 0) {
#pragma unroll
    for (int o = 0; o < 10; ++o) red[wv][o] = acc[o];
  }
  __syncthreads();
  if (threadIdx.x < 10) {
    const int o = threadIdx.x;
    out[b * 10 + o] =
        red[0][o] + red[1][o] + red[2][o] + red[3][o] + bias[o];
  }
}

// ---------------------------------------------------------------------------
extern "C" void kernel_launch(void* const* d_in, const int* in_sizes, int n_in,
                              void* d_out, int out_size, void* d_ws,
                              size_t ws_size, hipStream_t stream) {
  const float* x = (const float*)d_in[0];     // (128,28,28,2)
  const float* eps0 = (const float*)d_in[1];  // (6,512)
  const float* eps1 = (const float*)d_in[2];  // (10,1296)
  const float* W = (const float*)d_in[3];     // (10,6250)
  const float* bias = (const float*)d_in[4];  // (10,)
  float* out = (float*)d_out;                 // (128,10)

  float* ws = (float*)d_ws;
  float* e0m = ws;              // 3072 floats
  float* e1m = ws + 3072;       // 12960 floats
  float* h = ws + 16032;        // 128*26*26*6 = 519168 floats
  float* flat = ws + 535200;    // 128*25*25*10 = 800000 floats
  // total 1,335,200 floats = 5.35 MB of workspace

  hipLaunchKernelGGL(mask_kernel, dim3(63), dim3(256), 0, stream, eps0, eps1,
                     e0m, e1m);
  hipLaunchKernelGGL(stage1_kernel, dim3(338), dim3(256), 0, stream, x, e0m,
                     h);
  hipLaunchKernelGGL(stage2_kernel, dim3(313), dim3(256), 0, stream, h, e1m,
                     flat);
  hipLaunchKernelGGL(linear_kernel, dim3(128), dim3(256), 0, stream, flat, W,
                     bias, out);
}

// Round 3
// 120.758 us; speedup vs baseline: 1.5696x; 1.5696x over previous
//
#include <hip/hip_runtime.h>
#include <hip/hip_bf16.h>
#include <stdint.h>

typedef __attribute__((ext_vector_type(8))) short short8;
typedef __attribute__((ext_vector_type(4))) float floatx4;
typedef __attribute__((ext_vector_type(4))) int intx4;

// ---------------------------------------------------------------------------
// Threefry-2x32 (20 rounds), bit-exact vs JAX (verified round 2: absmax 0.0).
// ---------------------------------------------------------------------------
__device__ __forceinline__ void threefry2x32(uint32_t k0, uint32_t k1,
                                             uint32_t& x0, uint32_t& x1) {
  const uint32_t ks2 = k0 ^ k1 ^ 0x1BD11BDAu;
  uint32_t ks[3] = {k0, k1, ks2};
  const int rot[8] = {13, 15, 26, 6, 17, 29, 16, 24};
  x0 += ks[0];
  x1 += ks[1];
#pragma unroll
  for (int i = 0; i < 5; ++i) {
#pragma unroll
    for (int j = 0; j < 4; ++j) {
      const int r = rot[(i & 1) * 4 + j];
      x0 += x1;
      x1 = (x1 << r) | (x1 >> (32 - r));
      x1 ^= x0;
    }
    x0 += ks[(i + 1) % 3];
    x1 += ks[(i + 2) % 3] + (uint32_t)(i + 1);
  }
}

// masked value: (uniform(fold_in(key42,core))[e] < 0.8) * v / 0.8
// (partitionable PRF: counter=e -> (0,e), outputs XOR-folded; verified r2)
__device__ __forceinline__ float dropmask(int core, int e, float v) {
  uint32_t f0 = 0u, f1 = (uint32_t)core;
  threefry2x32(0u, 42u, f0, f1);
  uint32_t a = 0u, b = (uint32_t)e;
  threefry2x32(f0, f1, a, b);
  uint32_t bits = a ^ b;
  float u = __uint_as_float((bits >> 9) | 0x3F800000u) - 1.0f;
  float m = (u < 0.8f) ? 1.0f : 0.0f;
  return v * m / 0.8f;
}

__device__ __forceinline__ unsigned short f2bf(float f) {  // RNE
  uint32_t u = __float_as_uint(f);
  uint32_t r = u + 0x7fffu + ((u >> 16) & 1u);
  return (unsigned short)(r >> 16);
}

union B2I { __hip_bfloat162 b; int i; };
__device__ __forceinline__ int pk_bf16(float lo, float hi) {
  // v_cvt_pk_bf16_f32 on gfx950 via the HIP API
  B2I u;
  u.b = __float22bfloat162_rn(make_float2(lo, hi));
  return u.i;
}
union Frag { intx4 i; short8 s; };

// ---------------------------------------------------------------------------
// Prep: build both B matrices masked+bf16, PRE-SWIZZLED into MFMA B-fragment
// order. Bsw[c][lane][j] = B[k(c,lane>>4,j)][n=lane&15] so each wave chunk
// is ONE coalesced 16B/lane load.
//   stage1: k = c*32 + q*8 + j           (c<16, K=512, n<6 else 0)
//   stage2: octet t = 45*q + c; m=t/5, n_k=8*(t%5)+j  (c<45, K'=1440,
//           zero for n_k>=36 or n>=10)   [t-permutation makes n0 quad-free]
// ---------------------------------------------------------------------------
__global__ void prep_kernel(const float* __restrict__ eps0,
                            const float* __restrict__ eps1,
                            unsigned short* __restrict__ bsw1,
                            unsigned short* __restrict__ bsw2) {
  int idx = blockIdx.x * 256 + threadIdx.x;  // grid exactly 31232
  if (idx < 8192) {
    int j = idx & 7, L = (idx >> 3) & 63, c = idx >> 9;
    int o = L & 15, q = L >> 4;
    int k = c * 32 + q * 8 + j;
    float v = 0.0f;
    if (o < 6) {
      int e = o * 512 + k;
      v = dropmask(0, e, eps0[e]);
    }
    bsw1[idx] = f2bf(v);
  } else {
    int t2 = idx - 8192;  // < 23040 = 45*512
    int j = t2 & 7, L = (t2 >> 3) & 63, c = t2 >> 9;
    int o = L & 15, q = L >> 4;
    int t = 45 * q + c;
    int m = t / 5, nk = 8 * (t % 5) + j;
    float v = 0.0f;
    if (o < 10 && nk < 36) {
      int e = o * 1296 + m * 36 + nk;
      v = dropmask(1, e, eps1[e]);
    }
    bsw2[t2] = f2bf(v);
  }
}

// ---------------------------------------------------------------------------
// Stage 1 via MFMA: wave handles 16 pixels; A[p][k]=w6[k>>3]*w3[k&7] built
// in registers (lane's u-subset u=4c+q -> 16 regs, compile-time indexed).
// No LDS. B from global (16KB, L1-resident).
// ---------------------------------------------------------------------------
__global__ __launch_bounds__(256) void stage1_mfma(
    const float* __restrict__ x, const unsigned short* __restrict__ bsw1,
    float* __restrict__ h) {
  const int lane = threadIdx.x & 63;
  const int wave = (blockIdx.x * 256 + threadIdx.x) >> 6;  // 0..5407
  const int col = lane & 15, q = lane >> 4;
  const int pid = wave * 16 + col;  // this lane's pixel (A rows)
  const int b = pid / 676;
  const int rem = pid - b * 676;
  const int ii = rem / 26;
  const int jj = rem - ii * 26;

  const float2* x2 = (const float2*)x;
  float xv[9][2];
#pragma unroll
  for (int di = 0; di < 3; ++di)
#pragma unroll
    for (int dj = 0; dj < 3; ++dj) {
      float2 v = x2[(b * 28 + ii + di) * 28 + (jj + dj)];
      xv[di * 3 + dj][0] = v.x;
      xv[di * 3 + dj][1] = v.y;
    }

  // w3[j] = xv6[j>>2]*xv7[(j>>1)&1]*xv8[j&1]
  float w3[8];
#pragma unroll
  for (int j = 0; j < 8; ++j)
    w3[j] = xv[6][(j >> 2) & 1] * xv[7][(j >> 1) & 1] * xv[8][j & 1];

  // lane's w6 subset: u = 4c+q -> bits: c3c2c1c0 from pixels 0..3, q from 4,5
  const float wq = xv[4][(q >> 1) & 1] * xv[5][q & 1];
  float t01[4], t23[4];
#pragma unroll
  for (int a = 0; a < 2; ++a)
#pragma unroll
    for (int d = 0; d < 2; ++d) {
      t01[a * 2 + d] = xv[0][a] * xv[1][d];
      t23[a * 2 + d] = xv[2][a] * xv[3][d] * wq;
    }
  float w16[16];
#pragma unroll
  for (int c = 0; c < 16; ++c) w16[c] = t01[c >> 2] * t23[c & 3];

  floatx4 acc = {0.f, 0.f, 0.f, 0.f};
  const unsigned short* bp = bsw1 + lane * 8;
#pragma unroll
  for (int c = 0; c < 16; ++c) {
    Frag bf;
    bf.i = *(const intx4*)(bp + c * 512);
    const float w = w16[c];
    Frag af;
    af.i.x = pk_bf16(w * w3[0], w * w3[1]);
    af.i.y = pk_bf16(w * w3[2], w * w3[3]);
    af.i.z = pk_bf16(w * w3[4], w * w3[5]);
    af.i.w = pk_bf16(w * w3[6], w * w3[7]);
    acc = __builtin_amdgcn_mfma_f32_16x16x32_bf16(af.s, bf.s, acc, 0, 0, 0);
  }
  // D: col=lane&15 (output o), row=q*4+r (pixel local)
  if (col < 6) {
#pragma unroll
    for (int r = 0; r < 4; ++r) h[(wave * 16 + q * 4 + r) * 6 + col] = acc[r];
  }
}

// 6-way select, constant indices (wave-uniform-ish k, avoids scratch)
__device__ __forceinline__ float sel6(const float a[6], int k) {
  float r = a[0];
  r = (k == 1) ? a[1] : r;
  r = (k == 2) ? a[2] : r;
  r = (k == 3) ? a[3] : r;
  r = (k == 4) ? a[4] : r;
  r = (k == 5) ? a[5] : r;
  return r;
}

// ---------------------------------------------------------------------------
// Stage 2 via MFMA: K'=36*40=1440 (n padded to 40). Octet t=45q+c ->
// n0 = 8*(c%5) compile-time, m = 9q + c/5 -> 9-entry per-lane P01 subset.
// P23[40] fp32 in registers (4 zeros). No LDS.
// ---------------------------------------------------------------------------
__global__ __launch_bounds__(256) void stage2_mfma(
    const float* __restrict__ h, const unsigned short* __restrict__ bsw2,
    float* __restrict__ flat) {
  const int lane = threadIdx.x & 63;
  const int wave = (blockIdx.x * 256 + threadIdx.x) >> 6;  // 0..4999
  const int col = lane & 15, q = lane >> 4;
  const int pid = wave * 16 + col;
  const int b = pid / 625;
  const int rem = pid - b * 625;
  const int ii = rem / 25;
  const int jj = rem - ii * 25;

  const float* hp = h + ((b * 26 + ii) * 26 + jj) * 6;
  float h00[6], h01[6], h10[6], h11[6];
  const float2* hp2a = (const float2*)(hp);        // rows ii: 12 floats
  const float2* hp2b = (const float2*)(hp + 156);  // rows ii+1: 12 floats
#pragma unroll
  for (int t = 0; t < 3; ++t) {
    float2 v0 = hp2a[t], v1 = hp2a[t + 3], v2 = hp2b[t], v3 = hp2b[t + 3];
    h00[2 * t] = v0.x; h00[2 * t + 1] = v0.y;
    h01[2 * t] = v1.x; h01[2 * t + 1] = v1.y;
    h10[2 * t] = v2.x; h10[2 * t + 1] = v2.y;
    h11[2 * t] = v3.x; h11[2 * t + 1] = v3.y;
  }

  float P23[40];
#pragma unroll
  for (int a = 0; a < 6; ++a)
#pragma unroll
    for (int d = 0; d < 6; ++d) P23[a * 6 + d] = h10[a] * h11[d];
#pragma unroll
  for (int n = 36; n < 40; ++n) P23[n] = 0.0f;

  // P01 subset for this lane: m = 9q + d, d=0..8
  float P01s[9];
#pragma unroll
  for (int d = 0; d < 9; ++d) {
    const int m = 9 * q + d;           // m <= 35
    const int ia = (m * 43) >> 8;      // m/6 exact for m<54
    const int ic = m - ia * 6;
    P01s[d] = sel6(h00, ia) * sel6(h01, ic);
  }

  floatx4 acc = {0.f, 0.f, 0.f, 0.f};
  const unsigned short* bp = bsw2 + lane * 8;
#pragma unroll
  for (int c = 0; c < 45; ++c) {
    Frag bf;
    bf.i = *(const intx4*)(bp + c * 512);
    const float p01 = P01s[c / 5];
    const int n0 = 8 * (c % 5);
    Frag af;
    af.i.x = pk_bf16(p01 * P23[n0 + 0], p01 * P23[n0 + 1]);
    af.i.y = pk_bf16(p01 * P23[n0 + 2], p01 * P23[n0 + 3]);
    af.i.z = pk_bf16(p01 * P23[n0 + 4], p01 * P23[n0 + 5]);
    af.i.w = pk_bf16(p01 * P23[n0 + 6], p01 * P23[n0 + 7]);
    acc = __builtin_amdgcn_mfma_f32_16x16x32_bf16(af.s, bf.s, acc, 0, 0, 0);
  }
  if (col < 10) {
#pragma unroll
    for (int r = 0; r < 4; ++r)
      flat[(wave * 16 + q * 4 + r) * 10 + col] = acc[r];
  }
}

// ---------------------------------------------------------------------------
// Linear: out[b,o] = bias[o] + sum_f flat[b,f] * W[o,f]
// ---------------------------------------------------------------------------
__global__ __launch_bounds__(256) void linear_kernel(
    const float* __restrict__ flat, const float* __restrict__ W,
    const float* __restrict__ bias, float* __restrict__ out) {
  const int b = blockIdx.x;
  const float* fb = flat + b * 6250;
  float acc[10];
#pragma unroll
  for (int o = 0; o < 10; ++o) acc[o] = 0.0f;
  for (int f = threadIdx.x; f < 6250; f += 256) {
    const float v = fb[f];
#pragma unroll
    for (int o = 0; o < 10; ++o) acc[o] += v * W[o * 6250 + f];
  }
#pragma unroll
  for (int o = 0; o < 10; ++o) {
#pragma unroll
    for (int s = 32; s > 0; s >>= 1) acc[o] += __shfl_xor(acc[o], s, 64);
  }
  __shared__ float red[4][10];
  const int lane = threadIdx.x & 63, wv = threadIdx.x >> 6;
  if (lane == 0) {
#pragma unroll
    for (int o = 0; o < 10; ++o) red[wv][o] = acc[o];
  }
  __syncthreads();
  if (threadIdx.x < 10) {
    const int o = threadIdx.x;
    out[b * 10 + o] = red[0][o] + red[1][o] + red[2][o] + red[3][o] + bias[o];
  }
}

// ---------------------------------------------------------------------------
extern "C" void kernel_launch(void* const* d_in, const int* in_sizes, int n_in,
                              void* d_out, int out_size, void* d_ws,
                              size_t ws_size, hipStream_t stream) {
  const float* x = (const float*)d_in[0];     // (128,28,28,2)
  const float* eps0 = (const float*)d_in[1];  // (6,512)
  const float* eps1 = (const float*)d_in[2];  // (10,1296)
  const float* W = (const float*)d_in[3];     // (10,6250)
  const float* bias = (const float*)d_in[4];  // (10,)
  float* out = (float*)d_out;                 // (128,10)

  char* wsb = (char*)d_ws;
  unsigned short* bsw1 = (unsigned short*)wsb;            // 16384 B
  unsigned short* bsw2 = (unsigned short*)(wsb + 16384);  // 46080 B
  float* h = (float*)(wsb + 65536);     // 519168 floats = 2076672 B
  float* flat = (float*)(wsb + 65536 + 2076672);  // 800000 floats
  // total ~5.28 MB

  hipLaunchKernelGGL(prep_kernel, dim3(122), dim3(256), 0, stream, eps0, eps1,
                     bsw1, bsw2);
  hipLaunchKernelGGL(stage1_mfma, dim3(1352), dim3(256), 0, stream, x, bsw1,
                     h);
  hipLaunchKernelGGL(stage2_mfma, dim3(1250), dim3(256), 0, stream, h, bsw2,
                     flat);
  hipLaunchKernelGGL(linear_kernel, dim3(128), dim3(256), 0, stream, flat, W,
                     bias, out);
}

// Round 4
// 119.690 us; speedup vs baseline: 1.5836x; 1.0089x over previous
//
#include <hip/hip_runtime.h>
#include <hip/hip_bf16.h>
#include <stdint.h>

typedef __attribute__((ext_vector_type(8))) short short8;
typedef __attribute__((ext_vector_type(4))) float floatx4;
typedef __attribute__((ext_vector_type(4))) int intx4;

// ---------------------------------------------------------------------------
// Threefry-2x32 (20 rounds), bit-exact vs JAX (verified r2: absmax 0.0).
// ---------------------------------------------------------------------------
__device__ __forceinline__ void threefry2x32(uint32_t k0, uint32_t k1,
                                             uint32_t& x0, uint32_t& x1) {
  const uint32_t ks2 = k0 ^ k1 ^ 0x1BD11BDAu;
  uint32_t ks[3] = {k0, k1, ks2};
  const int rot[8] = {13, 15, 26, 6, 17, 29, 16, 24};
  x0 += ks[0];
  x1 += ks[1];
#pragma unroll
  for (int i = 0; i < 5; ++i) {
#pragma unroll
    for (int j = 0; j < 4; ++j) {
      const int r = rot[(i & 1) * 4 + j];
      x0 += x1;
      x1 = (x1 << r) | (x1 >> (32 - r));
      x1 ^= x0;
    }
    x0 += ks[(i + 1) % 3];
    x1 += ks[(i + 2) % 3] + (uint32_t)(i + 1);
  }
}

__device__ __forceinline__ float dropmask(int core, int e, float v) {
  uint32_t f0 = 0u, f1 = (uint32_t)core;
  threefry2x32(0u, 42u, f0, f1);
  uint32_t a = 0u, b = (uint32_t)e;
  threefry2x32(f0, f1, a, b);
  uint32_t bits = a ^ b;
  float u = __uint_as_float((bits >> 9) | 0x3F800000u) - 1.0f;
  float m = (u < 0.8f) ? 1.0f : 0.0f;
  return v * m / 0.8f;
}

__device__ __forceinline__ unsigned short f2bf(float f) {  // RNE
  uint32_t u = __float_as_uint(f);
  uint32_t r = u + 0x7fffu + ((u >> 16) & 1u);
  return (unsigned short)(r >> 16);
}

union B2I { __hip_bfloat162 b; int i; };
__device__ __forceinline__ int pk_bf16(float lo, float hi) {
  B2I u;
  u.b = __float22bfloat162_rn(make_float2(lo, hi));
  return u.i;
}
union Frag { intx4 i; short8 s; };

// ---------------------------------------------------------------------------
// Prep: masked bf16 B matrices, pre-swizzled into MFMA B-fragment order
// (verified r3).  stage1: k = c*32+q*8+j (c<16).  stage2: t=45q+c, m=t/5,
// nk=8*(t%5)+j (c<45, K'=1440, zeros for nk>=36 or col>=valid).
// ---------------------------------------------------------------------------
__global__ void prep_kernel(const float* __restrict__ eps0,
                            const float* __restrict__ eps1,
                            unsigned short* __restrict__ bsw1,
                            unsigned short* __restrict__ bsw2) {
  int idx = blockIdx.x * 256 + threadIdx.x;  // grid exactly 31232
  if (idx < 8192) {
    int j = idx & 7, L = (idx >> 3) & 63, c = idx >> 9;
    int o = L & 15, q = L >> 4;
    int k = c * 32 + q * 8 + j;
    float v = 0.0f;
    if (o < 6) {
      int e = o * 512 + k;
      v = dropmask(0, e, eps0[e]);
    }
    bsw1[idx] = f2bf(v);
  } else {
    int t2 = idx - 8192;  // < 23040 = 45*512
    int j = t2 & 7, L = (t2 >> 3) & 63, c = t2 >> 9;
    int o = L & 15, q = L >> 4;
    int t = 45 * q + c;
    int m = t / 5, nk = 8 * (t % 5) + j;
    float v = 0.0f;
    if (o < 10 && nk < 36) {
      int e = o * 1296 + m * 36 + nk;
      v = dropmask(1, e, eps1[e]);
    }
    bsw2[t2] = f2bf(v);
  }
}

// ---------------------------------------------------------------------------
// Stage 1 via MFMA, B staged in LDS (16 KB) once per block: the K-loop is
// ds_read_b128 + 12 VALU + MFMA per chunk -> no global-load latency chain.
// ---------------------------------------------------------------------------
__global__ __launch_bounds__(256) void stage1_mfma(
    const float* __restrict__ x, const unsigned short* __restrict__ bsw1,
    float* __restrict__ h) {
  __shared__ unsigned short Bs[8192];  // 16 chunks * 512 shorts
  {
    const intx4* src = (const intx4*)bsw1;
    intx4* dst = (intx4*)Bs;
#pragma unroll
    for (int t = 0; t < 4; ++t) dst[threadIdx.x + 256 * t] = src[threadIdx.x + 256 * t];
  }
  __syncthreads();

  const int lane = threadIdx.x & 63;
  const int wave = (blockIdx.x * 256 + threadIdx.x) >> 6;  // 0..5407
  const int col = lane & 15, q = lane >> 4;
  const int pid = wave * 16 + col;  // this lane's pixel (A row)
  const int b = pid / 676;
  const int rem = pid - b * 676;
  const int ii = rem / 26;
  const int jj = rem - ii * 26;

  const float2* x2 = (const float2*)x;
  float xv[9][2];
#pragma unroll
  for (int di = 0; di < 3; ++di)
#pragma unroll
    for (int dj = 0; dj < 3; ++dj) {
      float2 v = x2[(b * 28 + ii + di) * 28 + (jj + dj)];
      xv[di * 3 + dj][0] = v.x;
      xv[di * 3 + dj][1] = v.y;
    }

  float w3[8];
#pragma unroll
  for (int j = 0; j < 8; ++j)
    w3[j] = xv[6][(j >> 2) & 1] * xv[7][(j >> 1) & 1] * xv[8][j & 1];

  // u = 4c+q: c bits from pixels 0..3, q bits from pixels 4,5
  const float wq = xv[4][(q >> 1) & 1] * xv[5][q & 1];
  float t01[4], t23[4];
#pragma unroll
  for (int a = 0; a < 2; ++a)
#pragma unroll
    for (int d = 0; d < 2; ++d) {
      t01[a * 2 + d] = xv[0][a] * xv[1][d];
      t23[a * 2 + d] = xv[2][a] * xv[3][d] * wq;
    }
  float w16[16];
#pragma unroll
  for (int c = 0; c < 16; ++c) w16[c] = t01[c >> 2] * t23[c & 3];

  floatx4 acc = {0.f, 0.f, 0.f, 0.f};
  const unsigned short* bp = Bs + lane * 8;
#pragma unroll
  for (int c = 0; c < 16; ++c) {
    Frag bf;
    bf.i = *(const intx4*)(bp + c * 512);
    const float w = w16[c];
    Frag af;
    af.i.x = pk_bf16(w * w3[0], w * w3[1]);
    af.i.y = pk_bf16(w * w3[2], w * w3[3]);
    af.i.z = pk_bf16(w * w3[4], w * w3[5]);
    af.i.w = pk_bf16(w * w3[6], w * w3[7]);
    acc = __builtin_amdgcn_mfma_f32_16x16x32_bf16(af.s, bf.s, acc, 0, 0, 0);
  }
  if (col < 6) {
#pragma unroll
    for (int r = 0; r < 4; ++r) h[(wave * 16 + q * 4 + r) * 6 + col] = acc[r];
  }
}

// 6-way select, constant indices (avoids scratch for dynamic index)
__device__ __forceinline__ float sel6(const float a[6], int k) {
  float r = a[0];
  r = (k == 1) ? a[1] : r;
  r = (k == 2) ? a[2] : r;
  r = (k == 3) ? a[3] : r;
  r = (k == 4) ? a[4] : r;
  r = (k == 5) ? a[5] : r;
  return r;
}

// ---------------------------------------------------------------------------
// Stage 2 via MFMA, B staged in LDS (46080 B) once per block (3 blocks/CU).
// K'=1440; octet t=45q+c -> n0=8*(c%5) compile-time, m=9q+c/5.
// ---------------------------------------------------------------------------
__global__ __launch_bounds__(256) void stage2_mfma(
    const float* __restrict__ h, const unsigned short* __restrict__ bsw2,
    float* __restrict__ flat) {
  __shared__ unsigned short Bs[23040];  // 45 chunks * 512 shorts = 46080 B
  {
    const intx4* src = (const intx4*)bsw2;
    intx4* dst = (intx4*)Bs;
    for (int t = threadIdx.x; t < 2880; t += 256) dst[t] = src[t];
  }
  __syncthreads();

  const int lane = threadIdx.x & 63;
  const int wave = (blockIdx.x * 256 + threadIdx.x) >> 6;  // 0..4999
  const int col = lane & 15, q = lane >> 4;
  const int pid = wave * 16 + col;
  const int b = pid / 625;
  const int rem = pid - b * 625;
  const int ii = rem / 25;
  const int jj = rem - ii * 25;

  const float* hp = h + ((b * 26 + ii) * 26 + jj) * 6;
  float h00[6], h01[6], h10[6], h11[6];
  const float2* hp2a = (const float2*)(hp);
  const float2* hp2b = (const float2*)(hp + 156);
#pragma unroll
  for (int t = 0; t < 3; ++t) {
    float2 v0 = hp2a[t], v1 = hp2a[t + 3], v2 = hp2b[t], v3 = hp2b[t + 3];
    h00[2 * t] = v0.x; h00[2 * t + 1] = v0.y;
    h01[2 * t] = v1.x; h01[2 * t + 1] = v1.y;
    h10[2 * t] = v2.x; h10[2 * t + 1] = v2.y;
    h11[2 * t] = v3.x; h11[2 * t + 1] = v3.y;
  }

  float P23[40];
#pragma unroll
  for (int a = 0; a < 6; ++a)
#pragma unroll
    for (int d = 0; d < 6; ++d) P23[a * 6 + d] = h10[a] * h11[d];
#pragma unroll
  for (int n = 36; n < 40; ++n) P23[n] = 0.0f;

  float P01s[9];
#pragma unroll
  for (int d = 0; d < 9; ++d) {
    const int m = 9 * q + d;
    const int ia = (m * 43) >> 8;  // m/6 exact for m<54
    const int ic = m - ia * 6;
    P01s[d] = sel6(h00, ia) * sel6(h01, ic);
  }

  floatx4 acc = {0.f, 0.f, 0.f, 0.f};
  const unsigned short* bp = Bs + lane * 8;
#pragma unroll
  for (int c = 0; c < 45; ++c) {
    Frag bf;
    bf.i = *(const intx4*)(bp + c * 512);
    const float p01 = P01s[c / 5];
    const int n0 = 8 * (c % 5);
    Frag af;
    af.i.x = pk_bf16(p01 * P23[n0 + 0], p01 * P23[n0 + 1]);
    af.i.y = pk_bf16(p01 * P23[n0 + 2], p01 * P23[n0 + 3]);
    af.i.z = pk_bf16(p01 * P23[n0 + 4], p01 * P23[n0 + 5]);
    af.i.w = pk_bf16(p01 * P23[n0 + 6], p01 * P23[n0 + 7]);
    acc = __builtin_amdgcn_mfma_f32_16x16x32_bf16(af.s, bf.s, acc, 0, 0, 0);
  }
  if (col < 10) {
#pragma unroll
    for (int r = 0; r < 4; ++r)
      flat[(wave * 16 + q * 4 + r) * 10 + col] = acc[r];
  }
}

// ---------------------------------------------------------------------------
// Linear, split over f: grid (128 batch, 5 chunks of 1250). Block-reduce,
// then one atomicAdd per (block, o). out zero-initialized by zero_kernel.
// ---------------------------------------------------------------------------
__global__ void zero_kernel(float* __restrict__ out) {
  int t = blockIdx.x * 256 + threadIdx.x;
  if (t < 1280) out[t] = 0.0f;
}

__global__ __launch_bounds__(256) void linear_kernel(
    const float* __restrict__ flat, const float* __restrict__ W,
    const float* __restrict__ bias, float* __restrict__ out) {
  const int b = blockIdx.x;
  const int c = blockIdx.y;  // 0..4
  const float* fb = flat + b * 6250 + c * 1250;
  const float* Wc = W + c * 1250;
  float acc[10];
#pragma unroll
  for (int o = 0; o < 10; ++o) acc[o] = 0.0f;
  for (int f = threadIdx.x; f < 1250; f += 256) {
    const float v = fb[f];
#pragma unroll
    for (int o = 0; o < 10; ++o) acc[o] += v * Wc[o * 6250 + f];
  }
#pragma unroll
  for (int o = 0; o < 10; ++o) {
#pragma unroll
    for (int s = 32; s > 0; s >>= 1) acc[o] += __shfl_xor(acc[o], s, 64);
  }
  __shared__ float red[4][10];
  const int lane = threadIdx.x & 63, wv = threadIdx.x >> 6;
  if (lane == 0) {
#pragma unroll
    for (int o = 0; o < 10; ++o) red[wv][o] = acc[o];
  }
  __syncthreads();
  if (threadIdx.x < 10) {
    const int o = threadIdx.x;
    float r = red[0][o] + red[1][o] + red[2][o] + red[3][o];
    if (c == 0) r += bias[o];
    atomicAdd(&out[b * 10 + o], r);
  }
}

// ---------------------------------------------------------------------------
extern "C" void kernel_launch(void* const* d_in, const int* in_sizes, int n_in,
                              void* d_out, int out_size, void* d_ws,
                              size_t ws_size, hipStream_t stream) {
  const float* x = (const float*)d_in[0];     // (128,28,28,2)
  const float* eps0 = (const float*)d_in[1];  // (6,512)
  const float* eps1 = (const float*)d_in[2];  // (10,1296)
  const float* W = (const float*)d_in[3];     // (10,6250)
  const float* bias = (const float*)d_in[4];  // (10,)
  float* out = (float*)d_out;                 // (128,10)

  char* wsb = (char*)d_ws;
  unsigned short* bsw1 = (unsigned short*)wsb;            // 16384 B
  unsigned short* bsw2 = (unsigned short*)(wsb + 16384);  // 46080 B
  float* h = (float*)(wsb + 65536);               // 519168 floats
  float* flat = (float*)(wsb + 65536 + 2076672);  // 800000 floats

  hipLaunchKernelGGL(prep_kernel, dim3(122), dim3(256), 0, stream, eps0, eps1,
                     bsw1, bsw2);
  hipLaunchKernelGGL(zero_kernel, dim3(5), dim3(256), 0, stream, out);
  hipLaunchKernelGGL(stage1_mfma, dim3(1352), dim3(256), 0, stream, x, bsw1,
                     h);
  hipLaunchKernelGGL(stage2_mfma, dim3(1250), dim3(256), 0, stream, h, bsw2,
                     flat);
  hipLaunchKernelGGL(linear_kernel, dim3(128, 5), dim3(256), 0, stream, flat,
                     W, bias, out);
}